// Round 5
// baseline (176.280 us; speedup 1.0000x reference)
//
#include <hip/hip_runtime.h>

// Binary-weight dense: out[M,N] = scale * x[M,K] @ W[K,N], W = kernel ? +1 : -1
// M = 16384, K = 1024, N = 1024.
// R10: eliminate the xb (x->bf16) round-trip (128 MB of prep traffic) without
// repeating R8's mistake. R8 reg-staged A (global->reg->cvt->LDS) and the
// per-iter vmcnt drain serialized it. Here A is staged as RAW FP32 via
// global_load_lds (the proven DMA path, 32 KiB/tile) and converted
// fp32->bf16 at FRAGMENT-READ time in the compute phase (v_cvt_pk_bf16_f32,
// 32 instr/thread/K-step; VALU was 27% busy -> headroom; MFMA+VALU co-issue
// is free, m114). Accounting model from R5/R9: GEMM = ~41us K-loop (m97-rate)
// + ~10us epilogue burst; prep 22us; launches 6.6us. This round: prep shrinks
// to convert_w only (~4us), GEMM fetch +32MB, LDS 48KB -> 3 blocks/CU =
// 768 resident < 1024 grid -> staggered finish shrinks the write burst.
// A-swizzle (fp32, 16B chunks, 16/row): sw(r) = ((r&7)<<1)|((r>>3)&1);
// LDS[r][c] holds global chunk c^sw(r) (linear DMA dest + permuted source
// within each 256B row). Fragment group j reads chunks (2j)^sw, (2j+1)^sw;
// bank distribution matches the measured-zero-conflict bf16 scheme.

#define M_TOT 16384
#define N_TOT 1024
#define K_TOT 1024

typedef __attribute__((ext_vector_type(8))) short bf16x8;
typedef __attribute__((ext_vector_type(4))) float f32x4;
typedef __attribute__((ext_vector_type(4))) unsigned int u32x4;

__device__ __forceinline__ unsigned short f2bf(float f) {
    unsigned int u = __builtin_bit_cast(unsigned int, f);
    u += 0x7FFFu + ((u >> 16) & 1u);   // round-to-nearest-even
    return (unsigned short)(u >> 16);
}

// v_cvt_pk_bf16_f32: dst = {lo16=cvt(a), hi16=cvt(b)}, RNE (== f2bf).
__device__ __forceinline__ unsigned int cvt_pk_bf16(float a, float b) {
    unsigned int r;
    asm("v_cvt_pk_bf16_f32 %0, %1, %2" : "=v"(r) : "v"(a), "v"(b));
    return r;
}

// ---------------- prepass: W bools [k][n] -> +-1 bf16 [n][k] ----------------
// Mode detect inlined: int32 bools -> first 1024 words all 0/1; byte bools ->
// some word >1 w.p. ~1. First 4KB in-bounds in both encodings; deterministic.
__global__ __launch_bounds__(256) void convert_w(
    const void* __restrict__ w_raw, unsigned short* __restrict__ wt)
{
    __shared__ unsigned short tile[64 * 72];
    __shared__ int smode;
    const int tid = threadIdx.x;
    const int k0 = (blockIdx.x & 15) * 64;
    const int n0 = (blockIdx.x >> 4) * 64;
    const int row = tid >> 2;            // k-local
    const int seg = (tid & 3) * 16;      // n-local group of 16

    if (tid == 0) smode = 0;
    __syncthreads();
    {
        const unsigned int* k32 = (const unsigned int*)w_raw;
        int bad = 0;
        for (int i = tid; i < 1024; i += 256)
            bad |= (k32[i] > 1u) ? 1 : 0;
        if (bad) atomicOr(&smode, 1);
    }
    __syncthreads();

    if (smode == 0) {
        const unsigned int* w = (const unsigned int*)w_raw;
        const uint4* src = reinterpret_cast<const uint4*>(
            w + (size_t)(k0 + row) * N_TOT + n0 + seg);
        #pragma unroll
        for (int q = 0; q < 4; ++q) {
            uint4 v = src[q];
            ushort4 h;
            h.x = v.x ? 0x3F80u : 0xBF80u;
            h.y = v.y ? 0x3F80u : 0xBF80u;
            h.z = v.z ? 0x3F80u : 0xBF80u;
            h.w = v.w ? 0x3F80u : 0xBF80u;
            *reinterpret_cast<ushort4*>(&tile[row * 72 + seg + q * 4]) = h;
        }
    } else {
        const unsigned char* w = (const unsigned char*)w_raw;
        uint4 v = *reinterpret_cast<const uint4*>(
            w + (size_t)(k0 + row) * N_TOT + n0 + seg);
        unsigned char b[16];
        *reinterpret_cast<uint4*>(b) = v;
        #pragma unroll
        for (int q = 0; q < 4; ++q) {
            ushort4 h;
            h.x = b[q * 4 + 0] ? 0x3F80u : 0xBF80u;
            h.y = b[q * 4 + 1] ? 0x3F80u : 0xBF80u;
            h.z = b[q * 4 + 2] ? 0x3F80u : 0xBF80u;
            h.w = b[q * 4 + 3] ? 0x3F80u : 0xBF80u;
            *reinterpret_cast<ushort4*>(&tile[row * 72 + seg + q * 4]) = h;
        }
    }
    __syncthreads();
    {   // write-out: thread -> (n, 16 consecutive k)
        int n = tid >> 2, kseg = (tid & 3) * 16;
        ushort4 o[4];
        #pragma unroll
        for (int j = 0; j < 16; ++j)
            ((unsigned short*)o)[j] = tile[(kseg + j) * 72 + n];
        ushort4* dst = reinterpret_cast<ushort4*>(wt + (size_t)(n0 + n) * K_TOT + k0 + kseg);
        dst[0] = o[0]; dst[1] = o[1]; dst[2] = o[2]; dst[3] = o[3];
    }
}

// ------------- fused GEMM: out = scale * cvt_bf16(X_f32) @ BT(bf16)^T -------------
__global__ __launch_bounds__(256) void fused_gemm(
    const float* __restrict__ X,             // [M][K] fp32
    const unsigned short* __restrict__ BT,   // [N][K] bf16 (pre-transposed W)
    const float* __restrict__ scale_p, float* __restrict__ out)
{
    __shared__ float          As[128 * 64];  // 32 KiB fp32 (16B chunk = 4 floats)
    __shared__ unsigned short Bs[128 * 64];  // 16 KiB bf16 (16B chunk = 8 bf16)

    const int tid  = threadIdx.x;
    const int lane = tid & 63;
    const int wave = tid >> 6;
    const int wm = (wave & 1) * 64;
    const int wn = (wave >> 1) * 64;

    // XCD-aware swizzle: 8 blocks sharing an A m-strip keep the same
    // blockIdx%8 -> same XCD under round-robin dispatch -> one L2 fill/strip.
    const int j  = blockIdx.x & 7;
    const int s  = blockIdx.x >> 3;
    const int by = ((s >> 3) << 3) | j;   // 0..127
    const int bx = s & 7;                 // 0..7
    const int m0 = by * 128, n0 = bx * 128;

    const int fr = lane & 15, fq = lane >> 4;
    const float scale = scale_p[0];

    // B staging (proven R5 pattern): lane i -> row srow+(i>>3), chunk i&7;
    // source k-chunk = (i&7)^(i>>3) so LDS[r][c] holds chunk c^(r&7).
    const int srow = wave * 32 + (lane >> 3);
    const int skch = (lane & 7) ^ (lane >> 3);

    // A staging (fp32): 16 chunks/row; lane i -> row +(i>>4), dest chunk i&15,
    // source chunk (i&15)^sw(r), sw(r) = ((r&7)<<1)|((r>>3)&1).
    const int arow_l = lane >> 4;            // 0..3
    const int adch   = lane & 15;            // dest chunk (linear)

    f32x4 acc[4][4] = {};

    for (int k0 = 0; k0 < K_TOT; k0 += 64) {
        // A: 8 issues x 4 rows (wave covers rows wave*32 .. +32)
        #pragma unroll
        for (int q = 0; q < 8; ++q) {
            const int r  = wave * 32 + q * 4 + arow_l;
            const int sw = ((r & 7) << 1) | ((r >> 3) & 1);
            const float* g = X + (size_t)(m0 + r) * K_TOT + k0 + ((adch ^ sw) << 2);
            __builtin_amdgcn_global_load_lds(
                (const __attribute__((address_space(1))) void*)g,
                (__attribute__((address_space(3))) void*)&As[(wave * 32 + q * 4) * 64],
                16, 0, 0);
        }
        // B: 4 issues x 8 rows
        #pragma unroll
        for (int q = 0; q < 4; ++q) {
            const unsigned short* g = BT + (size_t)(n0 + srow + q * 8) * K_TOT + k0 + skch * 8;
            __builtin_amdgcn_global_load_lds(
                (const __attribute__((address_space(1))) void*)g,
                (__attribute__((address_space(3))) void*)&Bs[wave * 2048 + q * 512],
                16, 0, 0);
        }
        __syncthreads();

        #pragma unroll
        for (int ks = 0; ks < 2; ++ks) {
            // B fragments (bf16, as in R5)
            bf16x8 bfr[4];
            #pragma unroll
            for (int ni = 0; ni < 4; ++ni) {
                int r  = wn + ni * 16 + fr;
                int ch = (ks * 4 + fq) ^ (r & 7);
                bfr[ni] = *reinterpret_cast<const bf16x8*>(&Bs[r * 64 + ch * 8]);
            }
            // A fragments: two f32x4 LDS reads + packed cvt -> bf16x8
            bf16x8 af[4];
            #pragma unroll
            for (int mi = 0; mi < 4; ++mi) {
                int r  = wm + mi * 16 + fr;
                int sw = ((r & 7) << 1) | ((r >> 3) & 1);
                int g8 = ks * 4 + fq;                       // 8-float group
                f32x4 lo = *reinterpret_cast<const f32x4*>(&As[r * 64 + (((2 * g8)     ^ sw) << 2)]);
                f32x4 hi = *reinterpret_cast<const f32x4*>(&As[r * 64 + (((2 * g8 + 1) ^ sw) << 2)]);
                u32x4 p;
                p.x = cvt_pk_bf16(lo[0], lo[1]);
                p.y = cvt_pk_bf16(lo[2], lo[3]);
                p.z = cvt_pk_bf16(hi[0], hi[1]);
                p.w = cvt_pk_bf16(hi[2], hi[3]);
                af[mi] = __builtin_bit_cast(bf16x8, p);
            }
            #pragma unroll
            for (int mi = 0; mi < 4; ++mi)
                #pragma unroll
                for (int ni = 0; ni < 4; ++ni)
                    acc[mi][ni] = __builtin_amdgcn_mfma_f32_16x16x32_bf16(
                        af[mi], bfr[ni], acc[mi][ni], 0, 0, 0);
        }
        __syncthreads();
    }

    // epilogue: C/D layout col = fr, row = fq*4 + j  (m89/m91-verified)
    #pragma unroll
    for (int mi = 0; mi < 4; ++mi) {
        #pragma unroll
        for (int ni = 0; ni < 4; ++ni) {
            const int col  = n0 + wn + ni * 16 + fr;
            const int rowb = m0 + wm + mi * 16 + fq * 4;
            #pragma unroll
            for (int jj = 0; jj < 4; ++jj)
                out[(size_t)(rowb + jj) * N_TOT + col] = scale * acc[mi][ni][jj];
        }
    }
}

// ---------------- fallback (ws too small): fused kernel, int32 weights ----------------
#define BKP 40
__global__ __launch_bounds__(256, 2) void binary_dense_gemm(
    const float* __restrict__ x, const int* __restrict__ kern,
    const float* __restrict__ scale_p, float* __restrict__ out)
{
    __shared__ unsigned short Asf[128 * BKP];
    __shared__ unsigned short Bsf[128 * BKP];
    const int tid = threadIdx.x, lane = tid & 63, wave = tid >> 6;
    const int wm = (wave & 1) * 64, wn = (wave >> 1) * 64;
    const int bx = blockIdx.x & 7, by = blockIdx.x >> 3;
    const int m0 = by * 128, n0 = bx * 128;
    const float scale = scale_p[0];
    const int fr = lane & 15, fq = lane >> 4;
    f32x4 acc[4][4] = {};
    for (int k0 = 0; k0 < K_TOT; k0 += 32) {
        #pragma unroll
        for (int i = 0; i < 4; ++i) {
            int slot = tid + i * 256, row = slot >> 3, kg = (slot & 7) << 2;
            const float4 v = *reinterpret_cast<const float4*>(x + (size_t)(m0 + row) * K_TOT + k0 + kg);
            ushort4 h;
            h.x = f2bf(v.x); h.y = f2bf(v.y); h.z = f2bf(v.z); h.w = f2bf(v.w);
            *reinterpret_cast<ushort4*>(&Asf[row * BKP + kg]) = h;
        }
        #pragma unroll
        for (int i = 0; i < 4; ++i) {
            int slot = tid + i * 256, nl = slot & 127, kg = (slot >> 7) << 2;
            ushort4 h;
            h.x = kern[(size_t)(k0 + kg + 0) * N_TOT + n0 + nl] ? 0x3F80u : 0xBF80u;
            h.y = kern[(size_t)(k0 + kg + 1) * N_TOT + n0 + nl] ? 0x3F80u : 0xBF80u;
            h.z = kern[(size_t)(k0 + kg + 2) * N_TOT + n0 + nl] ? 0x3F80u : 0xBF80u;
            h.w = kern[(size_t)(k0 + kg + 3) * N_TOT + n0 + nl] ? 0x3F80u : 0xBF80u;
            *reinterpret_cast<ushort4*>(&Bsf[nl * BKP + kg]) = h;
        }
        __syncthreads();
        bf16x8 af[4], bfr[4];
        #pragma unroll
        for (int mi = 0; mi < 4; ++mi)
            af[mi] = *reinterpret_cast<const bf16x8*>(&Asf[(wm + mi * 16 + fr) * BKP + fq * 8]);
        #pragma unroll
        for (int ni = 0; ni < 4; ++ni)
            bfr[ni] = *reinterpret_cast<const bf16x8*>(&Bsf[(wn + ni * 16 + fr) * BKP + fq * 8]);
        #pragma unroll
        for (int mi = 0; mi < 4; ++mi)
            #pragma unroll
            for (int ni = 0; ni < 4; ++ni)
                acc[mi][ni] = __builtin_amdgcn_mfma_f32_16x16x32_bf16(af[mi], bfr[ni], acc[mi][ni], 0, 0, 0);
        __syncthreads();
    }
    #pragma unroll
    for (int mi = 0; mi < 4; ++mi)
        #pragma unroll
        for (int ni = 0; ni < 4; ++ni) {
            const int col = n0 + wn + ni * 16 + fr;
            const int rowb = m0 + wm + mi * 16 + fq * 4;
            #pragma unroll
            for (int jj = 0; jj < 4; ++jj)
                out[(size_t)(rowb + jj) * N_TOT + col] = scale * acc[mi][ni][jj];
        }
}

extern "C" void kernel_launch(void* const* d_in, const int* in_sizes, int n_in,
                              void* d_out, int out_size, void* d_ws, size_t ws_size,
                              hipStream_t stream) {
    const float* x     = (const float*)d_in[0];
    const void*  kern  = d_in[1];
    const float* scale = (const float*)d_in[2];
    float*       out   = (float*)d_out;

    const size_t wt_bytes = (size_t)N_TOT * K_TOT * 2;   // 2 MiB
    const size_t wt_off   = 256;                         // 16B-aligned
    if (ws_size >= wt_off + wt_bytes) {
        unsigned short* wt = (unsigned short*)((char*)d_ws + wt_off);
        hipLaunchKernelGGL(convert_w, dim3(256), dim3(256), 0, stream, kern, wt);
        hipLaunchKernelGGL(fused_gemm, dim3(1024), dim3(256), 0, stream,
                           x, wt, scale, out);
    } else {
        hipLaunchKernelGGL(binary_dense_gemm, dim3(1024), dim3(256), 0, stream,
                           x, (const int*)kern, scale, out);
    }
}

// Round 7
// 155.729 us; speedup vs baseline: 1.1320x; 1.1320x over previous
//
#include <hip/hip_runtime.h>

// Binary-weight dense: out[M,N] = scale * x[M,K] @ W[K,N], W = kernel ? +1 : -1
// M = 16384, K = 1024, N = 1024.
// R12 == R11 resubmitted: R6 bench died at the container level (no compile or
// test output -> infra flake, consistent with earlier acquire/push
// instability). Full re-audit found no deadlock: vmcnt ledger walked
// load-by-load (steady 4->6->8->vmcnt(4); every wait retires exactly the
// half-tile needed two phases later; tail i=7 p5 vmcnt(0) sound), barriers
// wave-uniform, WAR on buffer re-stage covered by per-wave lgkmcnt(0) +
// tail barrier, swizzle algebra and grid bijectivity re-verified.
//
// Design (R11): R9 pipeline (prep = convert_w + convert_x, one launch) +
// GEMM upgraded from the m97 2-barrier structure (~840 TF ceiling, 51-60us)
// to the 256^2 8-phase counted-vmcnt template (T2+T3+T4+T5; m201 1563 TF).
//   geometry: BM=BN=256 BK=64, 512 thr (8 waves 2Mx4N), per-wave 128x64,
//   acc[8][4]; LDS = 2ops x 2buf x 2khalf x 256x32 bf16 = 128 KB; grid 64x4=256
//   blocks = 1/CU; XCD-bijective map (same-by blocks share an XCD).
//   half-tile = K-half (256 rows x 32 k) staged just-in-time 4 phases ahead.
//   Wait ledger (items = half-tiles, 2 loads each; per-wave vmcnt):
//     prologue: stage tile0 {Ak0,Bk0,Ak1,Bk1}; vmcnt(4) -> Ak0,Bk0 landed; bar.
//     phase p (0..7): rb=p>>2 kk=(p>>1)&1 mh=p&1; ds_read A(mh,kk)[+B(kk) if mh0];
//       stage item p&3 of tile (p<4 ? 2i+1 -> buf1 : 2i+2 -> buf0);
//       bar; lgkmcnt(0); 16 MFMA; odd p: vmcnt(4) (i==7,p==5: vmcnt(0)); bar.
//   Swizzle: LDS[r][c] = global chunk c ^ ((r>>1)&3) within each K-half
//   (pre-swizzled source, linear DMA dest; uniform 8 lanes/bank-quad on frag
//   reads = free per m136). scale loaded only in the epilogue.

#define M_TOT 16384
#define N_TOT 1024
#define K_TOT 1024

typedef __attribute__((ext_vector_type(8))) short bf16x8;
typedef __attribute__((ext_vector_type(4))) float f32x4;

__device__ __forceinline__ unsigned short f2bf(float f) {
    unsigned int u = __builtin_bit_cast(unsigned int, f);
    u += 0x7FFFu + ((u >> 16) & 1u);   // round-to-nearest-even
    return (unsigned short)(u >> 16);
}

// ---------------- prep: convert_w (blocks 0..255) + convert_x (blocks 256+) ----------------
__global__ __launch_bounds__(256) void prep(
    const void* __restrict__ w_raw, unsigned short* __restrict__ wt,
    const float4* __restrict__ x, ushort4* __restrict__ xb)
{
    __shared__ unsigned short tile[64 * 72];
    __shared__ int smode;
    const int tid = threadIdx.x;

    if (blockIdx.x >= 256) {
        // ---- convert_x: 4096 blocks x 256 thr x 4 float4 = 64MB -> 32MB ----
        const int S = 4096 * 256;
        int g = (blockIdx.x - 256) * 256 + tid;
        #pragma unroll
        for (int j = 0; j < 4; ++j) {
            int idx = g + j * S;
            float4 v = x[idx];
            ushort4 h;
            h.x = f2bf(v.x); h.y = f2bf(v.y); h.z = f2bf(v.z); h.w = f2bf(v.w);
            xb[idx] = h;
        }
        return;
    }

    // ---- convert_w: bools [k][n] -> +-1 bf16 [n][k], mode detect inlined ----
    const int k0 = (blockIdx.x & 15) * 64;
    const int n0 = (blockIdx.x >> 4) * 64;
    const int row = tid >> 2;            // k-local
    const int seg = (tid & 3) * 16;      // n-local group of 16

    if (tid == 0) smode = 0;
    __syncthreads();
    {
        const unsigned int* k32 = (const unsigned int*)w_raw;
        int bad = 0;
        for (int i = tid; i < 1024; i += 256)
            bad |= (k32[i] > 1u) ? 1 : 0;
        if (bad) atomicOr(&smode, 1);
    }
    __syncthreads();

    if (smode == 0) {
        const unsigned int* w = (const unsigned int*)w_raw;
        const uint4* src = reinterpret_cast<const uint4*>(
            w + (size_t)(k0 + row) * N_TOT + n0 + seg);
        #pragma unroll
        for (int q = 0; q < 4; ++q) {
            uint4 v = src[q];
            ushort4 h;
            h.x = v.x ? 0x3F80u : 0xBF80u;
            h.y = v.y ? 0x3F80u : 0xBF80u;
            h.z = v.z ? 0x3F80u : 0xBF80u;
            h.w = v.w ? 0x3F80u : 0xBF80u;
            *reinterpret_cast<ushort4*>(&tile[row * 72 + seg + q * 4]) = h;
        }
    } else {
        const unsigned char* w = (const unsigned char*)w_raw;
        uint4 v = *reinterpret_cast<const uint4*>(
            w + (size_t)(k0 + row) * N_TOT + n0 + seg);
        unsigned char b[16];
        *reinterpret_cast<uint4*>(b) = v;
        #pragma unroll
        for (int q = 0; q < 4; ++q) {
            ushort4 h;
            h.x = b[q * 4 + 0] ? 0x3F80u : 0xBF80u;
            h.y = b[q * 4 + 1] ? 0x3F80u : 0xBF80u;
            h.z = b[q * 4 + 2] ? 0x3F80u : 0xBF80u;
            h.w = b[q * 4 + 3] ? 0x3F80u : 0xBF80u;
            *reinterpret_cast<ushort4*>(&tile[row * 72 + seg + q * 4]) = h;
        }
    }
    __syncthreads();
    {
        int n = tid >> 2, kseg = (tid & 3) * 16;
        ushort4 o[4];
        #pragma unroll
        for (int j = 0; j < 16; ++j)
            ((unsigned short*)o)[j] = tile[(kseg + j) * 72 + n];
        ushort4* dst = reinterpret_cast<ushort4*>(wt + (size_t)(n0 + n) * K_TOT + k0 + kseg);
        dst[0] = o[0]; dst[1] = o[1]; dst[2] = o[2]; dst[3] = o[3];
    }
}

// ---------------- 8-phase 256^2 GEMM: out = scale * A(bf16) @ BT(bf16)^T ----------------
#define STAGE(P0, P1, LDSA, BUF, H, T) do {                                        \
    const int _ko = (T) * 64 + (H) * 32;                                           \
    __builtin_amdgcn_global_load_lds(                                              \
        (const __attribute__((address_space(1))) void*)((P0) + _ko),               \
        (__attribute__((address_space(3))) void*)&(LDSA)[((BUF)*2+(H))*8192 + dst0],\
        16, 0, 0);                                                                 \
    __builtin_amdgcn_global_load_lds(                                              \
        (const __attribute__((address_space(1))) void*)((P1) + _ko),               \
        (__attribute__((address_space(3))) void*)&(LDSA)[((BUF)*2+(H))*8192 + dst1],\
        16, 0, 0);                                                                 \
} while (0)

__global__ __launch_bounds__(512, 2) void gemm8(
    const unsigned short* __restrict__ A,    // [M][K] bf16 (xb)
    const unsigned short* __restrict__ BT,   // [N][K] bf16 (pre-transposed W)
    const float* __restrict__ scale_p, float* __restrict__ out)
{
    // [op][buf][khalf][256 rows][32 bf16]; 64 KiB each
    __shared__ unsigned short As[2 * 2 * 256 * 32];
    __shared__ unsigned short Bs[2 * 2 * 256 * 32];

    const int tid  = threadIdx.x;
    const int lane = tid & 63;
    const int wave = tid >> 6;      // 0..7
    const int wr   = wave >> 2;     // 0..1 (M half)
    const int wc   = wave & 3;      // 0..3 (N quarter)

    // grid 256 = (by 0..63) x (bx 0..3); same-by blocks -> same XCD (g&7).
    const int g    = blockIdx.x;
    const int by   = ((g >> 3) >> 2) * 8 + (g & 7);
    const int bx   = (g >> 3) & 3;
    const int m0   = by * 256, n0 = bx * 256;

    const int fr = lane & 15, fq = lane >> 4;

    // staging map: issue covers local rows rr = wave*32 + (lane>>2) (+16),
    // dest chunk lane&3 (linear), source chunk (lane&3)^((rr>>1)&3)
    const int sd  = lane >> 2;
    const int sc  = (lane & 3) ^ ((lane >> 3) & 3);
    const int rr0 = wave * 32 + sd;
    const int rr1 = rr0 + 16;
    const unsigned short* pA0 = A  + (size_t)(m0 + rr0) * K_TOT + sc * 8;
    const unsigned short* pA1 = A  + (size_t)(m0 + rr1) * K_TOT + sc * 8;
    const unsigned short* pB0 = BT + (size_t)(n0 + rr0) * K_TOT + sc * 8;
    const unsigned short* pB1 = BT + (size_t)(n0 + rr1) * K_TOT + sc * 8;
    const int dst0 = wave * 1024;        // (wave*32+ 0)*32 shorts
    const int dst1 = dst0 + 512;         // (wave*32+16)*32

    // fragment read offsets: chunk = fq ^ ((r>>1)&3) = fq ^ ((fr>>1)&3)
    // (mi*16, wr*128, wc*64 are all == 0 mod 8 -> same for every sub-tile)
    const int chq  = fq ^ ((fr >> 1) & 3);
    const int aoff = (wr * 128 + fr) * 32 + chq * 8;
    const int boff = (wc * 64  + fr) * 32 + chq * 8;

    f32x4 acc[8][4] = {};
    bf16x8 bfr[4];

    // prologue: tile 0 -> buf0; wait Ak0,Bk0 (leave Ak1,Bk1 in flight)
    STAGE(pA0, pA1, As, 0, 0, 0);
    STAGE(pB0, pB1, Bs, 0, 0, 0);
    STAGE(pA0, pA1, As, 0, 1, 0);
    STAGE(pB0, pB1, Bs, 0, 1, 0);
    asm volatile("s_waitcnt vmcnt(4)" ::: "memory");
    __builtin_amdgcn_s_barrier();

    for (int i = 0; i < 8; ++i) {
        const int to  = 2 * i + 1;
        const int te2 = 2 * i + 2;
        #pragma unroll
        for (int p = 0; p < 8; ++p) {
            const int rb = p >> 2;           // buffer being read
            const int kk = (p >> 1) & 1;
            const int mh = p & 1;

            // --- ds_reads (from buf rb, half kk) ---
            bf16x8 af[4];
            if (mh == 0) {
                #pragma unroll
                for (int ni = 0; ni < 4; ++ni)
                    bfr[ni] = *reinterpret_cast<const bf16x8*>(
                        &Bs[(rb * 2 + kk) * 8192 + boff + ni * 512]);
            }
            #pragma unroll
            for (int mi2 = 0; mi2 < 4; ++mi2)
                af[mi2] = *reinterpret_cast<const bf16x8*>(
                    &As[(rb * 2 + kk) * 8192 + aoff + (mh * 4 + mi2) * 512]);

            // --- stage one half-tile (just-in-time, 4 phases ahead) ---
            {
                const int item = p & 3;               // 0:Ak0 1:Bk0 2:Ak1 3:Bk1
                const int ts   = (p < 4) ? to : te2;
                const int sb   = (p < 4) ? 1 : 0;
                if (ts < 16) {
                    const int h = item >> 1;
                    if ((item & 1) == 0) STAGE(pA0, pA1, As, sb, h, ts);
                    else                 STAGE(pB0, pB1, Bs, sb, h, ts);
                }
            }
            __builtin_amdgcn_sched_barrier(0);
            __builtin_amdgcn_s_barrier();
            asm volatile("s_waitcnt lgkmcnt(0)" ::: "memory");
            __builtin_amdgcn_sched_barrier(0);

            // --- 16 MFMA: C-quadrant (mh, all ni), K=32 slice kk ---
            __builtin_amdgcn_s_setprio(1);
            #pragma unroll
            for (int mi2 = 0; mi2 < 4; ++mi2)
                #pragma unroll
                for (int ni = 0; ni < 4; ++ni)
                    acc[mh * 4 + mi2][ni] = __builtin_amdgcn_mfma_f32_16x16x32_bf16(
                        af[mi2], bfr[ni], acc[mh * 4 + mi2][ni], 0, 0, 0);
            __builtin_amdgcn_s_setprio(0);
            __builtin_amdgcn_sched_barrier(0);

            if (p & 1) {
                if (i == 7 && p == 5) asm volatile("s_waitcnt vmcnt(0)" ::: "memory");
                else                  asm volatile("s_waitcnt vmcnt(4)" ::: "memory");
            }
            __builtin_amdgcn_s_barrier();
        }
    }

    // epilogue (scale loaded here so no VMEM op perturbs the counted waits)
    const float scale = scale_p[0];
    #pragma unroll
    for (int mi = 0; mi < 8; ++mi) {
        #pragma unroll
        for (int ni = 0; ni < 4; ++ni) {
            const int col  = n0 + wc * 64 + ni * 16 + fr;
            const int rowb = m0 + wr * 128 + mi * 16 + fq * 4;
            #pragma unroll
            for (int jj = 0; jj < 4; ++jj)
                out[(size_t)(rowb + jj) * N_TOT + col] = scale * acc[mi][ni][jj];
        }
    }
}

// ---------------- fallback (ws too small): fused kernel, int32 weights ----------------
#define BKP 40
__global__ __launch_bounds__(256, 2) void binary_dense_gemm(
    const float* __restrict__ x, const int* __restrict__ kern,
    const float* __restrict__ scale_p, float* __restrict__ out)
{
    __shared__ unsigned short Asf[128 * BKP];
    __shared__ unsigned short Bsf[128 * BKP];
    const int tid = threadIdx.x, lane = tid & 63, wave = tid >> 6;
    const int wm = (wave & 1) * 64, wn = (wave >> 1) * 64;
    const int bx = blockIdx.x & 7, by = blockIdx.x >> 3;
    const int m0 = by * 128, n0 = bx * 128;
    const float scale = scale_p[0];
    const int fr = lane & 15, fq = lane >> 4;
    f32x4 acc[4][4] = {};
    for (int k0 = 0; k0 < K_TOT; k0 += 32) {
        #pragma unroll
        for (int i = 0; i < 4; ++i) {
            int slot = tid + i * 256, row = slot >> 3, kg = (slot & 7) << 2;
            const float4 v = *reinterpret_cast<const float4*>(x + (size_t)(m0 + row) * K_TOT + k0 + kg);
            ushort4 h;
            h.x = f2bf(v.x); h.y = f2bf(v.y); h.z = f2bf(v.z); h.w = f2bf(v.w);
            *reinterpret_cast<ushort4*>(&Asf[row * BKP + kg]) = h;
        }
        #pragma unroll
        for (int i = 0; i < 4; ++i) {
            int slot = tid + i * 256, nl = slot & 127, kg = (slot >> 7) << 2;
            ushort4 h;
            h.x = kern[(size_t)(k0 + kg + 0) * N_TOT + n0 + nl] ? 0x3F80u : 0xBF80u;
            h.y = kern[(size_t)(k0 + kg + 1) * N_TOT + n0 + nl] ? 0x3F80u : 0xBF80u;
            h.z = kern[(size_t)(k0 + kg + 2) * N_TOT + n0 + nl] ? 0x3F80u : 0xBF80u;
            h.w = kern[(size_t)(k0 + kg + 3) * N_TOT + n0 + nl] ? 0x3F80u : 0xBF80u;
            *reinterpret_cast<ushort4*>(&Bsf[nl * BKP + kg]) = h;
        }
        __syncthreads();
        bf16x8 af[4], bfr[4];
        #pragma unroll
        for (int mi = 0; mi < 4; ++mi)
            af[mi] = *reinterpret_cast<const bf16x8*>(&Asf[(wm + mi * 16 + fr) * BKP + fq * 8]);
        #pragma unroll
        for (int ni = 0; ni < 4; ++ni)
            bfr[ni] = *reinterpret_cast<const bf16x8*>(&Bsf[(wn + ni * 16 + fr) * BKP + fq * 8]);
        #pragma unroll
        for (int mi = 0; mi < 4; ++mi)
            #pragma unroll
            for (int ni = 0; ni < 4; ++ni)
                acc[mi][ni] = __builtin_amdgcn_mfma_f32_16x16x32_bf16(af[mi], bfr[ni], acc[mi][ni], 0, 0, 0);
        __syncthreads();
    }
    #pragma unroll
    for (int mi = 0; mi < 4; ++mi)
        #pragma unroll
        for (int ni = 0; ni < 4; ++ni) {
            const int col = n0 + wn + ni * 16 + fr;
            const int rowb = m0 + wm + mi * 16 + fq * 4;
            #pragma unroll
            for (int jj = 0; jj < 4; ++jj)
                out[(size_t)(rowb + jj) * N_TOT + col] = scale * acc[mi][ni][jj];
        }
}

extern "C" void kernel_launch(void* const* d_in, const int* in_sizes, int n_in,
                              void* d_out, int out_size, void* d_ws, size_t ws_size,
                              hipStream_t stream) {
    const float* x     = (const float*)d_in[0];
    const void*  kern  = d_in[1];
    const float* scale = (const float*)d_in[2];
    float*       out   = (float*)d_out;

    const size_t xb_bytes = (size_t)M_TOT * K_TOT * 2;           // 32 MiB
    const size_t wt_bytes = (size_t)N_TOT * K_TOT * 2;           //  2 MiB
    const size_t xb_off   = 256;                                 // 16B-aligned
    if (ws_size >= xb_off + xb_bytes + wt_bytes) {
        unsigned short* xb = (unsigned short*)((char*)d_ws + xb_off);
        unsigned short* wt = (unsigned short*)((char*)d_ws + xb_off + xb_bytes);
        hipLaunchKernelGGL(prep, dim3(256 + 4096), dim3(256), 0, stream,
                           kern, wt, (const float4*)x, (ushort4*)xb);
        hipLaunchKernelGGL(gemm8, dim3(256), dim3(512), 0, stream,
                           xb, wt, scale, out);
    } else {
        hipLaunchKernelGGL(binary_dense_gemm, dim3(1024), dim3(256), 0, stream,
                           x, (const int*)kern, scale, out);
    }
}

// Round 8
// 153.948 us; speedup vs baseline: 1.1451x; 1.0116x over previous
//
#include <hip/hip_runtime.h>

// Binary-weight dense: out[M,N] = scale * x[M,K] @ W[K,N], W = kernel ? +1 : -1
// M = 16384, K = 1024, N = 1024.
// R13: R12's 8-phase 256^2 GEMM ran 49us (701 TF, MfmaUtil 25%) = 928 cyc/phase
// vs m201's ~412. Two deviations from the m201 discipline identified:
//  (1) staging was just-in-time (4 phases ahead) forcing vmcnt waits at EVERY
//      odd phase (4/iter). m201: stage each slot the phase after it frees
//      (5-6 phases before its read), waits ONLY at p3/p7 (2/iter, counted N).
//  (2) 3x sched_barrier(0) per phase (m141: over-pinning regresses). Keep only
//      the rule-18 one after lgkmcnt(0).
// New ledger (slots = {buf,khalf}, STAGE = 2 loads, vmcnt counts loads):
//   reads: p0-1 buf0kk0 | p2-3 buf0kk1 | p4-5 buf1kk0 | p6-7 buf1kk1
//   stage: p0 A/p1 B -> buf1kk1 = t(2i+1);  p2 A/p3 B -> buf0kk0 = t(2i+2);
//          p4 A/p5 B -> buf0kk1 = t(2i+2);  p6 A/p7 B -> buf1kk0 = t(2i+3)
//   (each slot staged right after its last read's tail barrier; WAR safe)
//   waits: p3-end vmcnt(4) -> lands prev p6-7 (t(2i+1)kk0, read p4) and this
//          p0-1 (t(2i+1)kk1, read p6); p7-end vmcnt(4) -> lands p2-5 (t(2i+2),
//          read next p0/p2). Tail: i==7 p3 -> vmcnt(0), p7 -> none.
//   prologue: t0kk0, t0kk1, t1kk0 (12 loads) + vmcnt(4) (t0 landed, t1kk0 in
//   flight, covered by first p3-end wait).
// Rest unchanged from R12 (prep, swizzle, XCD map, epilogue, fallback).

#define M_TOT 16384
#define N_TOT 1024
#define K_TOT 1024

typedef __attribute__((ext_vector_type(8))) short bf16x8;
typedef __attribute__((ext_vector_type(4))) float f32x4;

__device__ __forceinline__ unsigned short f2bf(float f) {
    unsigned int u = __builtin_bit_cast(unsigned int, f);
    u += 0x7FFFu + ((u >> 16) & 1u);   // round-to-nearest-even
    return (unsigned short)(u >> 16);
}

// ---------------- prep: convert_w (blocks 0..255) + convert_x (blocks 256+) ----------------
__global__ __launch_bounds__(256) void prep(
    const void* __restrict__ w_raw, unsigned short* __restrict__ wt,
    const float4* __restrict__ x, ushort4* __restrict__ xb)
{
    __shared__ unsigned short tile[64 * 72];
    __shared__ int smode;
    const int tid = threadIdx.x;

    if (blockIdx.x >= 256) {
        // ---- convert_x: 4096 blocks x 256 thr x 4 float4 = 64MB -> 32MB ----
        const int S = 4096 * 256;
        int g = (blockIdx.x - 256) * 256 + tid;
        #pragma unroll
        for (int j = 0; j < 4; ++j) {
            int idx = g + j * S;
            float4 v = x[idx];
            ushort4 h;
            h.x = f2bf(v.x); h.y = f2bf(v.y); h.z = f2bf(v.z); h.w = f2bf(v.w);
            xb[idx] = h;
        }
        return;
    }

    // ---- convert_w: bools [k][n] -> +-1 bf16 [n][k], mode detect inlined ----
    const int k0 = (blockIdx.x & 15) * 64;
    const int n0 = (blockIdx.x >> 4) * 64;
    const int row = tid >> 2;            // k-local
    const int seg = (tid & 3) * 16;      // n-local group of 16

    if (tid == 0) smode = 0;
    __syncthreads();
    {
        const unsigned int* k32 = (const unsigned int*)w_raw;
        int bad = 0;
        for (int i = tid; i < 1024; i += 256)
            bad |= (k32[i] > 1u) ? 1 : 0;
        if (bad) atomicOr(&smode, 1);
    }
    __syncthreads();

    if (smode == 0) {
        const unsigned int* w = (const unsigned int*)w_raw;
        const uint4* src = reinterpret_cast<const uint4*>(
            w + (size_t)(k0 + row) * N_TOT + n0 + seg);
        #pragma unroll
        for (int q = 0; q < 4; ++q) {
            uint4 v = src[q];
            ushort4 h;
            h.x = v.x ? 0x3F80u : 0xBF80u;
            h.y = v.y ? 0x3F80u : 0xBF80u;
            h.z = v.z ? 0x3F80u : 0xBF80u;
            h.w = v.w ? 0x3F80u : 0xBF80u;
            *reinterpret_cast<ushort4*>(&tile[row * 72 + seg + q * 4]) = h;
        }
    } else {
        const unsigned char* w = (const unsigned char*)w_raw;
        uint4 v = *reinterpret_cast<const uint4*>(
            w + (size_t)(k0 + row) * N_TOT + n0 + seg);
        unsigned char b[16];
        *reinterpret_cast<uint4*>(b) = v;
        #pragma unroll
        for (int q = 0; q < 4; ++q) {
            ushort4 h;
            h.x = b[q * 4 + 0] ? 0x3F80u : 0xBF80u;
            h.y = b[q * 4 + 1] ? 0x3F80u : 0xBF80u;
            h.z = b[q * 4 + 2] ? 0x3F80u : 0xBF80u;
            h.w = b[q * 4 + 3] ? 0x3F80u : 0xBF80u;
            *reinterpret_cast<ushort4*>(&tile[row * 72 + seg + q * 4]) = h;
        }
    }
    __syncthreads();
    {
        int n = tid >> 2, kseg = (tid & 3) * 16;
        ushort4 o[4];
        #pragma unroll
        for (int j = 0; j < 16; ++j)
            ((unsigned short*)o)[j] = tile[(kseg + j) * 72 + n];
        ushort4* dst = reinterpret_cast<ushort4*>(wt + (size_t)(n0 + n) * K_TOT + k0 + kseg);
        dst[0] = o[0]; dst[1] = o[1]; dst[2] = o[2]; dst[3] = o[3];
    }
}

// ---------------- 8-phase 256^2 GEMM: out = scale * A(bf16) @ BT(bf16)^T ----------------
#define STAGE(P0, P1, LDSA, BUF, H, T) do {                                        \
    const int _ko = (T) * 64 + (H) * 32;                                           \
    __builtin_amdgcn_global_load_lds(                                              \
        (const __attribute__((address_space(1))) void*)((P0) + _ko),               \
        (__attribute__((address_space(3))) void*)&(LDSA)[((BUF)*2+(H))*8192 + dst0],\
        16, 0, 0);                                                                 \
    __builtin_amdgcn_global_load_lds(                                              \
        (const __attribute__((address_space(1))) void*)((P1) + _ko),               \
        (__attribute__((address_space(3))) void*)&(LDSA)[((BUF)*2+(H))*8192 + dst1],\
        16, 0, 0);                                                                 \
} while (0)

__global__ __launch_bounds__(512, 2) void gemm8(
    const unsigned short* __restrict__ A,    // [M][K] bf16 (xb)
    const unsigned short* __restrict__ BT,   // [N][K] bf16 (pre-transposed W)
    const float* __restrict__ scale_p, float* __restrict__ out)
{
    // [op][buf][khalf][256 rows][32 bf16]; 64 KiB each
    __shared__ unsigned short As[2 * 2 * 256 * 32];
    __shared__ unsigned short Bs[2 * 2 * 256 * 32];

    const int tid  = threadIdx.x;
    const int lane = tid & 63;
    const int wave = tid >> 6;      // 0..7
    const int wr   = wave >> 2;     // 0..1 (M half)
    const int wc   = wave & 3;      // 0..3 (N quarter)

    // grid 256 = (by 0..63) x (bx 0..3); same-by blocks -> same XCD (g&7).
    const int g    = blockIdx.x;
    const int by   = ((g >> 3) >> 2) * 8 + (g & 7);
    const int bx   = (g >> 3) & 3;
    const int m0   = by * 256, n0 = bx * 256;

    const int fr = lane & 15, fq = lane >> 4;

    // staging map: rows rr = wave*32 + (lane>>2) (+16), dest chunk lane&3
    // (linear), source chunk (lane&3)^((rr>>1)&3)
    const int sd  = lane >> 2;
    const int sc  = (lane & 3) ^ ((lane >> 3) & 3);
    const int rr0 = wave * 32 + sd;
    const int rr1 = rr0 + 16;
    const unsigned short* pA0 = A  + (size_t)(m0 + rr0) * K_TOT + sc * 8;
    const unsigned short* pA1 = A  + (size_t)(m0 + rr1) * K_TOT + sc * 8;
    const unsigned short* pB0 = BT + (size_t)(n0 + rr0) * K_TOT + sc * 8;
    const unsigned short* pB1 = BT + (size_t)(n0 + rr1) * K_TOT + sc * 8;
    const int dst0 = wave * 1024;        // (wave*32+ 0)*32 shorts
    const int dst1 = dst0 + 512;         // (wave*32+16)*32

    // fragment read offsets: chunk = fq ^ ((r>>1)&3) = fq ^ ((fr>>1)&3)
    const int chq  = fq ^ ((fr >> 1) & 3);
    const int aoff = (wr * 128 + fr) * 32 + chq * 8;
    const int boff = (wc * 64  + fr) * 32 + chq * 8;

    f32x4 acc[8][4] = {};
    bf16x8 bfr[4];

    // prologue: t0 (both halves) + t1kk0 -> 12 loads; vmcnt(4) lands t0.
    STAGE(pA0, pA1, As, 0, 0, 0);
    STAGE(pB0, pB1, Bs, 0, 0, 0);
    STAGE(pA0, pA1, As, 0, 1, 0);
    STAGE(pB0, pB1, Bs, 0, 1, 0);
    STAGE(pA0, pA1, As, 1, 0, 1);
    STAGE(pB0, pB1, Bs, 1, 0, 1);
    asm volatile("s_waitcnt vmcnt(4)" ::: "memory");
    __builtin_amdgcn_s_barrier();

    for (int i = 0; i < 8; ++i) {
        #pragma unroll
        for (int p = 0; p < 8; ++p) {
            const int rb = p >> 2;           // buffer being read
            const int kk = (p >> 1) & 1;
            const int mh = p & 1;

            // --- ds_reads (from buf rb, half kk) ---
            bf16x8 af[4];
            if (mh == 0) {
                #pragma unroll
                for (int ni = 0; ni < 4; ++ni)
                    bfr[ni] = *reinterpret_cast<const bf16x8*>(
                        &Bs[(rb * 2 + kk) * 8192 + boff + ni * 512]);
            }
            #pragma unroll
            for (int mi2 = 0; mi2 < 4; ++mi2)
                af[mi2] = *reinterpret_cast<const bf16x8*>(
                    &As[(rb * 2 + kk) * 8192 + aoff + (mh * 4 + mi2) * 512]);

            // --- stage (early: slot staged the phase after it frees) ---
            {
                const int tile = (p < 2) ? (2 * i + 1) : (p < 6 ? 2 * i + 2 : 2 * i + 3);
                const int sb   = (p < 2 || p >= 6) ? 1 : 0;
                const int h    = 1 ^ ((p >> 1) & 1);   // p0-1:1 p2-3:0 p4-5:1 p6-7:0
                if (tile < 16) {
                    if ((p & 1) == 0) STAGE(pA0, pA1, As, sb, h, tile);
                    else              STAGE(pB0, pB1, Bs, sb, h, tile);
                }
            }
            __builtin_amdgcn_s_barrier();
            asm volatile("s_waitcnt lgkmcnt(0)" ::: "memory");
            __builtin_amdgcn_sched_barrier(0);

            // --- 16 MFMA: C-quadrant (mh, all ni), K=32 slice kk ---
            __builtin_amdgcn_s_setprio(1);
            #pragma unroll
            for (int mi2 = 0; mi2 < 4; ++mi2)
                #pragma unroll
                for (int ni = 0; ni < 4; ++ni)
                    acc[mh * 4 + mi2][ni] = __builtin_amdgcn_mfma_f32_16x16x32_bf16(
                        af[mi2], bfr[ni], acc[mh * 4 + mi2][ni], 0, 0, 0);
            __builtin_amdgcn_s_setprio(0);

            // --- counted waits: only p3 and p7 (m201 discipline) ---
            if (p == 3) {
                if (i == 7) asm volatile("s_waitcnt vmcnt(0)" ::: "memory");
                else        asm volatile("s_waitcnt vmcnt(4)" ::: "memory");
            } else if (p == 7) {
                if (i < 7)  asm volatile("s_waitcnt vmcnt(4)" ::: "memory");
            }
            __builtin_amdgcn_s_barrier();
        }
    }

    // epilogue (scale loaded here so no VMEM op perturbs the counted waits)
    const float scale = scale_p[0];
    #pragma unroll
    for (int mi = 0; mi < 8; ++mi) {
        #pragma unroll
        for (int ni = 0; ni < 4; ++ni) {
            const int col  = n0 + wc * 64 + ni * 16 + fr;
            const int rowb = m0 + wr * 128 + mi * 16 + fq * 4;
            #pragma unroll
            for (int jj = 0; jj < 4; ++jj)
                out[(size_t)(rowb + jj) * N_TOT + col] = scale * acc[mi][ni][jj];
        }
    }
}

// ---------------- fallback (ws too small): fused kernel, int32 weights ----------------
#define BKP 40
__global__ __launch_bounds__(256, 2) void binary_dense_gemm(
    const float* __restrict__ x, const int* __restrict__ kern,
    const float* __restrict__ scale_p, float* __restrict__ out)
{
    __shared__ unsigned short Asf[128 * BKP];
    __shared__ unsigned short Bsf[128 * BKP];
    const int tid = threadIdx.x, lane = tid & 63, wave = tid >> 6;
    const int wm = (wave & 1) * 64, wn = (wave >> 1) * 64;
    const int bx = blockIdx.x & 7, by = blockIdx.x >> 3;
    const int m0 = by * 128, n0 = bx * 128;
    const float scale = scale_p[0];
    const int fr = lane & 15, fq = lane >> 4;
    f32x4 acc[4][4] = {};
    for (int k0 = 0; k0 < K_TOT; k0 += 32) {
        #pragma unroll
        for (int i = 0; i < 4; ++i) {
            int slot = tid + i * 256, row = slot >> 3, kg = (slot & 7) << 2;
            const float4 v = *reinterpret_cast<const float4*>(x + (size_t)(m0 + row) * K_TOT + k0 + kg);
            ushort4 h;
            h.x = f2bf(v.x); h.y = f2bf(v.y); h.z = f2bf(v.z); h.w = f2bf(v.w);
            *reinterpret_cast<ushort4*>(&Asf[row * BKP + kg]) = h;
        }
        #pragma unroll
        for (int i = 0; i < 4; ++i) {
            int slot = tid + i * 256, nl = slot & 127, kg = (slot >> 7) << 2;
            ushort4 h;
            h.x = kern[(size_t)(k0 + kg + 0) * N_TOT + n0 + nl] ? 0x3F80u : 0xBF80u;
            h.y = kern[(size_t)(k0 + kg + 1) * N_TOT + n0 + nl] ? 0x3F80u : 0xBF80u;
            h.z = kern[(size_t)(k0 + kg + 2) * N_TOT + n0 + nl] ? 0x3F80u : 0xBF80u;
            h.w = kern[(size_t)(k0 + kg + 3) * N_TOT + n0 + nl] ? 0x3F80u : 0xBF80u;
            *reinterpret_cast<ushort4*>(&Bsf[nl * BKP + kg]) = h;
        }
        __syncthreads();
        bf16x8 af[4], bfr[4];
        #pragma unroll
        for (int mi = 0; mi < 4; ++mi)
            af[mi] = *reinterpret_cast<const bf16x8*>(&Asf[(wm + mi * 16 + fr) * BKP + fq * 8]);
        #pragma unroll
        for (int ni = 0; ni < 4; ++ni)
            bfr[ni] = *reinterpret_cast<const bf16x8*>(&Bsf[(wn + ni * 16 + fr) * BKP + fq * 8]);
        #pragma unroll
        for (int mi = 0; mi < 4; ++mi)
            #pragma unroll
            for (int ni = 0; ni < 4; ++ni)
                acc[mi][ni] = __builtin_amdgcn_mfma_f32_16x16x32_bf16(af[mi], bfr[ni], acc[mi][ni], 0, 0, 0);
        __syncthreads();
    }
    #pragma unroll
    for (int mi = 0; mi < 4; ++mi)
        #pragma unroll
        for (int ni = 0; ni < 4; ++ni) {
            const int col = n0 + wn + ni * 16 + fr;
            const int rowb = m0 + wm + mi * 16 + fq * 4;
            #pragma unroll
            for (int jj = 0; jj < 4; ++jj)
                out[(size_t)(rowb + jj) * N_TOT + col] = scale * acc[mi][ni][jj];
        }
}

extern "C" void kernel_launch(void* const* d_in, const int* in_sizes, int n_in,
                              void* d_out, int out_size, void* d_ws, size_t ws_size,
                              hipStream_t stream) {
    const float* x     = (const float*)d_in[0];
    const void*  kern  = d_in[1];
    const float* scale = (const float*)d_in[2];
    float*       out   = (float*)d_out;

    const size_t xb_bytes = (size_t)M_TOT * K_TOT * 2;           // 32 MiB
    const size_t wt_bytes = (size_t)N_TOT * K_TOT * 2;           //  2 MiB
    const size_t xb_off   = 256;                                 // 16B-aligned
    if (ws_size >= xb_off + xb_bytes + wt_bytes) {
        unsigned short* xb = (unsigned short*)((char*)d_ws + xb_off);
        unsigned short* wt = (unsigned short*)((char*)d_ws + xb_off + xb_bytes);
        hipLaunchKernelGGL(prep, dim3(256 + 4096), dim3(256), 0, stream,
                           kern, wt, (const float4*)x, (ushort4*)xb);
        hipLaunchKernelGGL(gemm8, dim3(256), dim3(512), 0, stream,
                           xb, wt, scale, out);
    } else {
        hipLaunchKernelGGL(binary_dense_gemm, dim3(1024), dim3(256), 0, stream,
                           x, (const int*)kern, scale, out);
    }
}